// Round 7
// baseline (240.003 us; speedup 1.0000x reference)
//
#include <hip/hip_runtime.h>
#include <hip/hip_bf16.h>

// CARAFE pipeline, 3 kernels, latency/occupancy-optimized.
// x: (4, 256, 64, 64) fp32
// w_down: (128, 256) ; b_down: (128)
// w_enc: (100, 128, 3, 3) ; b_enc: (100)
// w_out: (256, 256) ; b_out: (256)
// out z: (4, 256, 128, 128) fp32
//
// prep:      wcomb bf16 [384][256] = [w_down ; w_out] ; wrb bf16 [112][1152]
// dual_gemm: x -> t1T bf16 [n*4096][128] (+b_down) ; xoT bf16 [n*4096][256]
//            16-px tiles, 1024 blocks, 4 blocks/CU, swizzled LDS
// carafe3:   conv3x3(MFMA)+b_enc -> softmax(25) -> reassembly + b_out -> z
//            grid (64 tiles, 4 oc, 4 n) = 1024 blocks, 53 KB LDS, 3 blocks/CU
//
// MFMA v_mfma_f32_16x16x32_bf16 (guide §3, m89-verified):
//   A-frag: row = lane&15, k = (lane>>4)*8 + j
//   B-frag: col = lane&15, k = (lane>>4)*8 + j
//   C/D:    col = lane&15, row = (lane>>4)*4 + r
// Conv C-frag -> softmax mapping: co = 16*mf + 4*l4 + r = 4k+p => k = 4*mf+l4, p = r.

#define NB    4
#define NPIX  4096

typedef short s16x8 __attribute__((ext_vector_type(8)));
typedef float f32x4 __attribute__((ext_vector_type(4)));

#define MFMA16(a, b, c) __builtin_amdgcn_mfma_f32_16x16x32_bf16((a), (b), (c), 0, 0, 0)

__device__ __forceinline__ ushort f2b(float f) {
    __hip_bfloat16 h = __float2bfloat16(f);
    return *(ushort*)&h;
}
__device__ __forceinline__ float b2f(ushort u) {
    unsigned v = ((unsigned)u) << 16;
    return *(float*)&v;
}

// ---------------------------------------------------------------------------
// prep: weight casts/reorders. 227,328 elements, grid 888 x 256.
// ---------------------------------------------------------------------------
__global__ __launch_bounds__(256) void prep_kernel(
    const float* __restrict__ wd, const float* __restrict__ wo,
    const float* __restrict__ we,
    ushort* __restrict__ wcomb, ushort* __restrict__ wrb)
{
    int idx = blockIdx.x * 256 + threadIdx.x;
    if (idx < 98304) {
        float v = (idx < 32768) ? wd[idx] : wo[idx - 32768];
        wcomb[idx] = f2b(v);
    } else if (idx < 227328) {
        int i = idx - 98304;
        int co = i / 1152, k = i - co * 1152;
        int tap = k >> 7, c = k & 127;
        float v = (co < 100) ? we[(co * 128 + c) * 9 + tap] : 0.0f;
        wrb[i] = f2b(v);
    }
}

// ---------------------------------------------------------------------------
// dual_gemm: Out[pix][0..127] = t1T (+b_down) ; [128..383] = xoT.
// Grid (256, NB) = 1024 blocks x 256 threads. 16-pixel tile, 8.4 KB LDS,
// 4 blocks/CU. Each wave owns 96 output channels (6 MFMA col-frags).
// LDS tile XOR-swizzled in 8-ushort blocks (T2 pattern) -> conflict-light.
// ---------------------------------------------------------------------------
__global__ __launch_bounds__(256, 4) void dual_gemm_kernel(
    const float*  __restrict__ X,      // [NB][256][4096]
    const ushort* __restrict__ Wcomb,  // [384][256]
    const float*  __restrict__ b_down, // [128]
    ushort* __restrict__ T1t,          // [NB*4096][128]
    ushort* __restrict__ XOt)          // [NB*4096][256]
{
    __shared__ __attribute__((aligned(16))) ushort xs[16 * 264];
    const int n = blockIdx.y, p0 = blockIdx.x * 16;
    const int tid = threadIdx.x, lane = tid & 63, wid = tid >> 6;
    const int l15 = lane & 15, l4 = lane >> 4;

    // stage + transpose-cast: thread = (px-quad tid&3, channel tid>>2), 4 passes
    {
        const int pq = tid & 3;
        const float* src = X + (size_t)n * 256 * NPIX + p0 + pq * 4;
        #pragma unroll
        for (int pass = 0; pass < 4; pass++) {
            int c = pass * 64 + (tid >> 2);
            float4 v = *(const float4*)&src[(size_t)c * NPIX];
            float vv[4] = {v.x, v.y, v.z, v.w};
            #pragma unroll
            for (int j = 0; j < 4; j++) {
                int px = pq * 4 + j;
                xs[px * 264 + (c ^ ((px & 7) << 3))] = f2b(vv[j]);
            }
        }
    }
    __syncthreads();

    const int crow = wid * 96;      // each wave: 96 channels
    f32x4 acc[6] = {};
    #pragma unroll
    for (int ks = 0; ks < 8; ks++) {
        int k0 = ks * 32 + l4 * 8;
        s16x8 a = *(const s16x8*)&xs[l15 * 264 + (k0 ^ ((l15 & 7) << 3))];
        #pragma unroll
        for (int cf = 0; cf < 6; cf++) {
            s16x8 b = *(const s16x8*)&Wcomb[(size_t)(crow + cf * 16 + l15) * 256 + k0];
            acc[cf] = MFMA16(a, b, acc[cf]);
        }
    }

    #pragma unroll
    for (int cf = 0; cf < 6; cf++) {
        int cbase = crow + cf * 16;       // wave-uniform
        int c = cbase + l15;
        if (cbase < 128) {
            float bb = b_down[c];
            #pragma unroll
            for (int r = 0; r < 4; r++) {
                int pix = p0 + l4 * 4 + r;
                T1t[(size_t)(n * NPIX + pix) * 128 + c] = f2b(acc[cf][r] + bb);
            }
        } else {
            int c2 = c - 128;
            #pragma unroll
            for (int r = 0; r < 4; r++) {
                int pix = p0 + l4 * 4 + r;
                XOt[(size_t)(n * NPIX + pix) * 256 + c2] = f2b(acc[cf][r]);
            }
        }
    }
}

// ---------------------------------------------------------------------------
// carafe3: conv3x3(MFMA) + softmax + reassembly + pixel-shuffle, per oc-chunk.
// Grid (64 tiles, 4 oc, NB) = 1024 blocks x 256 threads (4 waves).
// LDS 53,056 B -> 3 blocks/CU:
//   region1 (27,200 B): hs ushort[100][136]  ->  sml f32 stride-100 (rot-swz)
//   region2 (25,856 B): eld f32 [64][101]    ->  xs ushort[144][72] (blk-XOR)
// xo halo loads issued before first barrier (latency hidden under hs stage).
// ---------------------------------------------------------------------------
__global__ __launch_bounds__(256, 3) void carafe3_kernel(
    const ushort* __restrict__ T1t,  // [NB*4096][128]
    const ushort* __restrict__ Wr,   // [112][1152]
    const float*  __restrict__ Benc, // [100]
    const ushort* __restrict__ XOt,  // [NB*4096][256]
    const float*  __restrict__ Bout, // [256]
    float* __restrict__ Z)           // [NB][256][128][128]
{
    __shared__ __attribute__((aligned(16))) char smem[27200 + 25856];
    ushort* hs  = (ushort*)smem;             // [100][136]
    float*  sml = (float*)smem;              // 64 rows, stride 100 words
    float*  eld = (float*)(smem + 27200);    // [64][101]
    ushort* xsu = (ushort*)(smem + 27200);   // [144][72]

    const int tile = blockIdx.x, oc = blockIdx.y, n = blockIdx.z;
    const int h0 = (tile >> 3) * 8, w0 = (tile & 7) * 8;
    const int tid = threadIdx.x, lane = tid & 63, wid = tid >> 6;
    const int l15 = lane & 15, l4 = lane >> 4;

    // ---- phase 1: stage t1 halo; issue xo halo loads early ----
    for (int u = tid; u < 1600; u += 256) {
        int hp = u >> 4, ch = u & 15;
        int r = hp / 10, s = hp - r * 10;
        int gh = h0 - 1 + r, gw = w0 - 1 + s;
        s16x8 v = {};
        if ((unsigned)gh < 64u && (unsigned)gw < 64u)
            v = *(const s16x8*)&T1t[((size_t)n * NPIX + gh * 64 + gw) * 128 + ch * 8];
        *(s16x8*)&hs[hp * 136 + ch * 8] = v;
    }
    ushort4 xoreg[9];
    #pragma unroll
    for (int t = 0; t < 9; t++) {
        int u = tid + t * 256;                 // 2304 = 144 px x 16 ch-quads
        int hp = u >> 4, cg = u & 15;
        int r = hp / 12, s = hp - r * 12;
        int gh = h0 - 2 + r, gw = w0 - 2 + s;
        ushort4 v = make_ushort4(0, 0, 0, 0);
        if ((unsigned)gh < 64u && (unsigned)gw < 64u)
            v = *(const ushort4*)&XOt[((size_t)n * NPIX + gh * 64 + gw) * 256 + oc * 64 + cg * 4];
        xoreg[t] = v;
    }
    __syncthreads();

    // ---- phase 2: conv via MFMA (each wave owns 16 pixels) ----
    {
        const int pl = wid * 16 + l15;
        const int ph_ = pl >> 3, pw_ = pl & 7;
        f32x4 cacc[7] = {};
        for (int tap = 0; tap < 9; tap++) {
            int dy = tap / 3, dx = tap - dy * 3;
            int hp = (ph_ + dy) * 10 + pw_ + dx;
            const ushort* hrow = &hs[hp * 136 + l4 * 8];
            const ushort* wrow = &Wr[(size_t)l15 * 1152 + tap * 128 + l4 * 8];
            #pragma unroll
            for (int cb = 0; cb < 4; cb++) {
                s16x8 b = *(const s16x8*)&hrow[cb * 32];
                #pragma unroll
                for (int mf = 0; mf < 7; mf++) {
                    s16x8 a = *(const s16x8*)&wrow[(size_t)mf * 16 * 1152 + cb * 32];
                    cacc[mf] = MFMA16(a, b, cacc[mf]);
                }
            }
        }
        #pragma unroll
        for (int mf = 0; mf < 7; mf++) {
            #pragma unroll
            for (int r = 0; r < 4; r++) {
                int co = mf * 16 + l4 * 4 + r;
                if (co < 100) eld[pl * 101 + co] = cacc[mf][r] + Benc[co];
            }
        }
    }
    __syncthreads();

    // ---- phase 3: softmax over 25 taps; rotation-swizzled store to sml ----
    {
        int p = tid & 3, pix = tid >> 2;
        int s = (pix >> 1) & 7;
        float v[25];
        float mx = -1e30f;
        #pragma unroll
        for (int k = 0; k < 25; k++) { v[k] = eld[pix * 101 + 4 * k + p]; mx = fmaxf(mx, v[k]); }
        float ssum = 0.0f;
        #pragma unroll
        for (int k = 0; k < 25; k++) { v[k] = __expf(v[k] - mx); ssum += v[k]; }
        float inv = 1.0f / ssum;
        #pragma unroll
        for (int k = 0; k < 25; k++) {
            int blk = k + s; if (blk >= 25) blk -= 25;
            sml[pix * 100 + blk * 4 + p] = v[k] * inv;
        }
    }
    __syncthreads();

    // ---- phase 4: write xo halo regs -> xs (block-XOR swizzle) ----
    #pragma unroll
    for (int t = 0; t < 9; t++) {
        int u = tid + t * 256;
        int hp = u >> 4, cg = u & 15;
        int blk = (cg >> 1) ^ (hp & 7);
        *(ushort4*)&xsu[hp * 72 + blk * 8 + (cg & 1) * 4] = xoreg[t];
    }
    __syncthreads();

    // ---- phase 5: reassembly + bias + pixel-shuffle, float4 Z stores ----
    const int pw2 = tid & 3;           // pw = 2*pw2, 2*pw2+1
    const int ph  = (tid >> 2) & 7;
    const int og  = tid >> 5;          // 8-channel group (0..7)
    const int pix0 = ph * 8 + pw2 * 2;
    const int s0 = (pix0 >> 1) & 7;

    float acc[8][8] = {};   // [ch][px*4 + p]
    for (int k = 0; k < 25; k++) {
        int di = k / 5, dj = k - di * 5;
        int blk = k + s0; if (blk >= 25) blk -= 25;
        f32x4 wv0 = *(const f32x4*)&sml[pix0 * 100 + blk * 4];
        f32x4 wv1 = *(const f32x4*)&sml[(pix0 + 1) * 100 + blk * 4];
        int b0 = (ph + di) * 12 + pw2 * 2 + dj;
        int b1 = b0 + 1;
        s16x8 x0 = *(const s16x8*)&xsu[b0 * 72 + ((og ^ (b0 & 7)) << 3)];
        s16x8 x1 = *(const s16x8*)&xsu[b1 * 72 + ((og ^ (b1 & 7)) << 3)];
        #pragma unroll
        for (int i = 0; i < 8; i++) {
            float f0 = b2f((ushort)x0[i]);
            float f1 = b2f((ushort)x1[i]);
            acc[i][0] += f0 * wv0[0];
            acc[i][1] += f0 * wv0[1];
            acc[i][2] += f0 * wv0[2];
            acc[i][3] += f0 * wv0[3];
            acc[i][4] += f1 * wv1[0];
            acc[i][5] += f1 * wv1[1];
            acc[i][6] += f1 * wv1[2];
            acc[i][7] += f1 * wv1[3];
        }
    }

    const int gh = h0 + ph;
    #pragma unroll
    for (int i = 0; i < 8; i++) {
        int o = oc * 64 + og * 8 + i;
        float bb = Bout[o];
        float4 v0 = make_float4(acc[i][0] + bb, acc[i][1] + bb, acc[i][4] + bb, acc[i][5] + bb);
        float4 v1 = make_float4(acc[i][2] + bb, acc[i][3] + bb, acc[i][6] + bb, acc[i][7] + bb);
        size_t zb = (((size_t)n * 256 + o) * 128 + 2 * gh) * 128 + 2 * w0 + 4 * pw2;
        *(float4*)&Z[zb]       = v0;
        *(float4*)&Z[zb + 128] = v1;
    }
}

// ---------------------------------------------------------------------------
extern "C" void kernel_launch(void* const* d_in, const int* in_sizes, int n_in,
                              void* d_out, int out_size, void* d_ws, size_t ws_size,
                              hipStream_t stream) {
    const float* x      = (const float*)d_in[0];
    const float* w_down = (const float*)d_in[1];
    const float* b_down = (const float*)d_in[2];
    const float* w_enc  = (const float*)d_in[3];
    const float* b_enc  = (const float*)d_in[4];
    const float* w_out  = (const float*)d_in[5];
    const float* b_out  = (const float*)d_in[6];
    float* z = (float*)d_out;

    // workspace layout (ushort elements)
    ushort* t1T   = (ushort*)d_ws;          // 4*4096*128 = 2,097,152
    ushort* xoT   = t1T + 2097152;          // 4*4096*256 = 4,194,304
    ushort* wcomb = xoT + 4194304;          // 384*256    =    98,304
    ushort* wrb   = wcomb + 98304;          // 112*1152   =   129,024

    prep_kernel<<<888, 256, 0, stream>>>(w_down, w_out, w_enc, wcomb, wrb);
    dual_gemm_kernel<<<dim3(256, NB), 256, 0, stream>>>(x, wcomb, b_down, t1T, xoT);
    carafe3_kernel<<<dim3(64, 4, NB), 256, 0, stream>>>(t1T, wrb, b_enc, xoT, b_out, z);
}

// Round 8
// 174.586 us; speedup vs baseline: 1.3747x; 1.3747x over previous
//
#include <hip/hip_runtime.h>
#include <hip/hip_bf16.h>

// CARAFE pipeline, 3 kernels.
// x: (4, 256, 64, 64) fp32
// w_down: (128, 256) ; b_down: (128)
// w_enc: (100, 128, 3, 3) ; b_enc: (100)
// w_out: (256, 256) ; b_out: (256)
// out z: (4, 256, 128, 128) fp32
//
// prep:          wcomb bf16 [384][256] = [w_down ; w_out] ; wrb bf16 [112][1152]
// dual_gemm:     x -> t1T bf16 [n*4096][128] (+b_down) ; xoT bf16 [n*4096][256]
//                16-px tiles, 1024 blocks, 4 blocks/CU
// carafe_fused2: conv3x3(MFMA, ONCE per tile) -> softmax(25) -> 4 oc-chunks of
//                reassembly + b_out + pixel-shuffle -> z
//                4x8-px tiles, 512 blocks x 512 thr, 42.5 KB LDS (2 blk/CU),
//                xo-halo register-prefetched one chunk ahead (T14).
//
// MFMA v_mfma_f32_16x16x32_bf16 (guide §3, m89-verified):
//   A-frag: row = lane&15, k = (lane>>4)*8 + j
//   B-frag: col = lane&15, k = (lane>>4)*8 + j
//   C/D:    col = lane&15, row = (lane>>4)*4 + r
// Conv C-frag -> softmax mapping: co = 16*mf + 4*l4 + r = 4k+p => k = 4*mf+l4, p = r.

#define NB    4
#define NPIX  4096

typedef short s16x8 __attribute__((ext_vector_type(8)));
typedef float f32x4 __attribute__((ext_vector_type(4)));

#define MFMA16(a, b, c) __builtin_amdgcn_mfma_f32_16x16x32_bf16((a), (b), (c), 0, 0, 0)

__device__ __forceinline__ ushort f2b(float f) {
    __hip_bfloat16 h = __float2bfloat16(f);
    return *(ushort*)&h;
}
__device__ __forceinline__ float b2f(ushort u) {
    unsigned v = ((unsigned)u) << 16;
    return *(float*)&v;
}

// ---------------------------------------------------------------------------
// prep: weight casts/reorders. 227,328 elements, grid 888 x 256.
// ---------------------------------------------------------------------------
__global__ __launch_bounds__(256) void prep_kernel(
    const float* __restrict__ wd, const float* __restrict__ wo,
    const float* __restrict__ we,
    ushort* __restrict__ wcomb, ushort* __restrict__ wrb)
{
    int idx = blockIdx.x * 256 + threadIdx.x;
    if (idx < 98304) {
        float v = (idx < 32768) ? wd[idx] : wo[idx - 32768];
        wcomb[idx] = f2b(v);
    } else if (idx < 227328) {
        int i = idx - 98304;
        int co = i / 1152, k = i - co * 1152;
        int tap = k >> 7, c = k & 127;
        float v = (co < 100) ? we[(co * 128 + c) * 9 + tap] : 0.0f;
        wrb[i] = f2b(v);
    }
}

// ---------------------------------------------------------------------------
// dual_gemm: Out[pix][0..127] = t1T (+b_down) ; [128..383] = xoT.
// Grid (256, NB) = 1024 blocks x 256 threads. 16-pixel tile, 8.4 KB LDS,
// 4 blocks/CU. Each wave owns 96 output channels (6 MFMA col-frags).
// ---------------------------------------------------------------------------
__global__ __launch_bounds__(256, 4) void dual_gemm_kernel(
    const float*  __restrict__ X,      // [NB][256][4096]
    const ushort* __restrict__ Wcomb,  // [384][256]
    const float*  __restrict__ b_down, // [128]
    ushort* __restrict__ T1t,          // [NB*4096][128]
    ushort* __restrict__ XOt)          // [NB*4096][256]
{
    __shared__ __attribute__((aligned(16))) ushort xs[16 * 264];
    const int n = blockIdx.y, p0 = blockIdx.x * 16;
    const int tid = threadIdx.x, lane = tid & 63, wid = tid >> 6;
    const int l15 = lane & 15, l4 = lane >> 4;

    // stage + transpose-cast: thread = (px-quad tid&3, channel tid>>2), 4 passes
    {
        const int pq = tid & 3;
        const float* src = X + (size_t)n * 256 * NPIX + p0 + pq * 4;
        #pragma unroll
        for (int pass = 0; pass < 4; pass++) {
            int c = pass * 64 + (tid >> 2);
            float4 v = *(const float4*)&src[(size_t)c * NPIX];
            float vv[4] = {v.x, v.y, v.z, v.w};
            #pragma unroll
            for (int j = 0; j < 4; j++) {
                int px = pq * 4 + j;
                xs[px * 264 + (c ^ ((px & 7) << 3))] = f2b(vv[j]);
            }
        }
    }
    __syncthreads();

    const int crow = wid * 96;      // each wave: 96 channels
    f32x4 acc[6] = {};
    #pragma unroll
    for (int ks = 0; ks < 8; ks++) {
        int k0 = ks * 32 + l4 * 8;
        s16x8 a = *(const s16x8*)&xs[l15 * 264 + (k0 ^ ((l15 & 7) << 3))];
        #pragma unroll
        for (int cf = 0; cf < 6; cf++) {
            s16x8 b = *(const s16x8*)&Wcomb[(size_t)(crow + cf * 16 + l15) * 256 + k0];
            acc[cf] = MFMA16(a, b, acc[cf]);
        }
    }

    #pragma unroll
    for (int cf = 0; cf < 6; cf++) {
        int cbase = crow + cf * 16;       // wave-uniform
        int c = cbase + l15;
        if (cbase < 128) {
            float bb = b_down[c];
            #pragma unroll
            for (int r = 0; r < 4; r++) {
                int pix = p0 + l4 * 4 + r;
                T1t[(size_t)(n * NPIX + pix) * 128 + c] = f2b(acc[cf][r] + bb);
            }
        } else {
            int c2 = c - 128;
            #pragma unroll
            for (int r = 0; r < 4; r++) {
                int pix = p0 + l4 * 4 + r;
                XOt[(size_t)(n * NPIX + pix) * 256 + c2] = f2b(acc[cf][r]);
            }
        }
    }
}

// ---------------------------------------------------------------------------
// carafe_fused2: conv3x3 (once) -> softmax -> 4 oc-chunk reassembly -> z.
// Grid (128 tiles, NB) = 512 blocks x 512 threads (8 waves).
// Tile = 4 rows x 8 cols of low-res pixels.
// LDS 42,496 B -> 2 blocks/CU:
//   region A [0, 16384):      hs ushort[60][136] (t1 halo) -> sml f32[32][100]
//   region B [16384, 42496):  eld f32[32][101]  ->  xs f32[96][68]
// Bank derivations:
//   sml: word = 100*pix + 4*blk + p, blk = (k + 4*(pix&1)) % 25.
//        16B-slot = (pix + blk) mod 8 = (q + 4(q&1) + k) mod 8, q = pix&7:
//        q -> q + 4(q&1) is a permutation of 0..7  => conflict-free.
//   xs reads: f32x4 at word 68*hp + 4*og: slot = (hp + og) mod 8 -> <=4-way.
//   xs writes: f32x4 per (hp, cg): slot = (hp + cg) mod 8, lanes cg 0..15 at
//        fixed hp -> 2 lanes/slot -> free.
// ---------------------------------------------------------------------------
__global__ __launch_bounds__(512, 2) void carafe_fused2_kernel(
    const ushort* __restrict__ T1t,  // [NB*4096][128]
    const ushort* __restrict__ Wr,   // [112][1152]
    const float*  __restrict__ Benc, // [100]
    const ushort* __restrict__ XOt,  // [NB*4096][256]
    const float*  __restrict__ Bout, // [256]
    float* __restrict__ Z)           // [NB][256][128][128]
{
    __shared__ __attribute__((aligned(16))) char smem[42496];
    ushort* hs  = (ushort*)smem;              // [60][136]  16,320 B
    float*  sml = (float*)smem;               // [32][100]  12,800 B (aliases hs)
    float*  eld = (float*)(smem + 16384);     // [32][101]  12,928 B
    float*  xs  = (float*)(smem + 16384);     // [96][68]   26,112 B (aliases eld)

    const int tile = blockIdx.x, n = blockIdx.y;
    const int h0 = (tile >> 3) * 4, w0 = (tile & 7) * 8;
    const int tid = threadIdx.x, lane = tid & 63, wid = tid >> 6;
    const int l15 = lane & 15, l4 = lane >> 4;

    // ---- prefetch xo halo chunk 0 into regs (completes under conv) ----
    ushort4 xoA[3], xoB[3];
    #pragma unroll
    for (int rr = 0; rr < 3; rr++) {
        int u = tid + rr * 512;            // 1536 = 96 halo px x 16 ch-quads
        int hp = u >> 4, cg = u & 15;
        int r = hp / 12, s = hp - r * 12;
        int gh = h0 - 2 + r, gw = w0 - 2 + s;
        ushort4 v = make_ushort4(0, 0, 0, 0);
        if ((unsigned)gh < 64u && (unsigned)gw < 64u)
            v = *(const ushort4*)&XOt[((size_t)n * NPIX + gh * 64 + gw) * 256 + cg * 4];
        xoA[rr] = v;
    }

    // ---- phase 1: stage t1 halo (6x10 px x 128 ch) ----
    for (int u = tid; u < 960; u += 512) {
        int r = u / 160, rem = u - r * 160;
        int s = rem >> 4, q = rem & 15;
        int gh = h0 - 1 + r, gw = w0 - 1 + s;
        s16x8 v = {};
        if ((unsigned)gh < 64u && (unsigned)gw < 64u)
            v = *(const s16x8*)&T1t[((size_t)n * NPIX + gh * 64 + gw) * 128 + q * 8];
        *(s16x8*)&hs[(r * 10 + s) * 136 + q * 8] = v;
    }
    __syncthreads();

    // ---- phase 2: conv via MFMA, once. 8 waves = 2 px-groups x 4 mf-groups ----
    {
        const int pg = wid & 1, mg = wid >> 1;    // mf = 2mg (and 2mg+1 if mg<3)
        const int pl = pg * 16 + l15;
        const int ph_ = pl >> 3, pw_ = pl & 7;
        f32x4 c0 = {}, c1 = {};
        for (int tap = 0; tap < 9; tap++) {
            int dy = tap / 3, dx = tap - dy * 3;
            const ushort* hrow = &hs[((ph_ + dy) * 10 + pw_ + dx) * 136 + l4 * 8];
            const ushort* wrow = &Wr[(size_t)(mg * 32 + l15) * 1152 + tap * 128 + l4 * 8];
            #pragma unroll
            for (int cb = 0; cb < 4; cb++) {
                s16x8 b = *(const s16x8*)&hrow[cb * 32];
                c0 = MFMA16(*(const s16x8*)&wrow[cb * 32], b, c0);
                if (mg < 3)
                    c1 = MFMA16(*(const s16x8*)&wrow[16 * 1152 + cb * 32], b, c1);
            }
        }
        #pragma unroll
        for (int r = 0; r < 4; r++) {
            int co0 = mg * 32 + l4 * 4 + r;
            if (co0 < 100) eld[pl * 101 + co0] = c0[r] + Benc[co0];
            if (mg < 3)    eld[pl * 101 + co0 + 16] = c1[r] + Benc[co0 + 16];
        }
    }
    __syncthreads();

    // ---- phase 3: softmax over 25 taps (32 px x 4 p = 128 work items) ----
    if (tid < 128) {
        int p = tid & 3, pix = tid >> 2;
        int s4 = (pix & 1) * 4;
        float v[25];
        float mx = -1e30f;
        #pragma unroll
        for (int k = 0; k < 25; k++) { v[k] = eld[pix * 101 + 4 * k + p]; mx = fmaxf(mx, v[k]); }
        float ssum = 0.0f;
        #pragma unroll
        for (int k = 0; k < 25; k++) { v[k] = __expf(v[k] - mx); ssum += v[k]; }
        float inv = 1.0f / ssum;
        #pragma unroll
        for (int k = 0; k < 25; k++) {
            int blk = k + s4; if (blk >= 25) blk -= 25;
            sml[pix * 100 + blk * 4 + p] = v[k] * inv;
        }
    }
    __syncthreads();

    // ---- phase 4: 4 oc-chunks: write xs, prefetch next, compute, store ----
    const int pix = tid & 31, og = tid >> 5;   // og: 16 groups of 4 ch
    const int ph = pix >> 3, pw = pix & 7;
    const int s4 = (pix & 1) * 4;
    const int gh = h0 + ph, gw = w0 + pw;

    auto chunk = [&](int it, ushort4 (&cur)[3], ushort4 (&nxt)[3], bool last) {
        // write xs from prefetched regs: f32x4 per (hp, cg)
        #pragma unroll
        for (int rr = 0; rr < 3; rr++) {
            int u = tid + rr * 512;
            int hp = u >> 4, cg = u & 15;
            f32x4 f;
            f[0] = b2f(cur[rr].x); f[1] = b2f(cur[rr].y);
            f[2] = b2f(cur[rr].z); f[3] = b2f(cur[rr].w);
            *(f32x4*)&xs[hp * 68 + cg * 4] = f;
        }
        // prefetch next chunk (latency hides under compute below)
        if (!last) {
            #pragma unroll
            for (int rr = 0; rr < 3; rr++) {
                int u = tid + rr * 512;
                int hp = u >> 4, cg = u & 15;
                int r = hp / 12, s = hp - r * 12;
                int gh2 = h0 - 2 + r, gw2 = w0 - 2 + s;
                ushort4 v = make_ushort4(0, 0, 0, 0);
                if ((unsigned)gh2 < 64u && (unsigned)gw2 < 64u)
                    v = *(const ushort4*)&XOt[((size_t)n * NPIX + gh2 * 64 + gw2) * 256
                                              + (it + 1) * 64 + cg * 4];
                nxt[rr] = v;
            }
        }
        __syncthreads();

        float acc[4][4] = {};
        for (int k = 0; k < 25; k++) {
            int di = k / 5, dj = k - di * 5;
            int blk = k + s4; if (blk >= 25) blk -= 25;
            f32x4 wv = *(const f32x4*)&sml[pix * 100 + blk * 4];
            f32x4 xv = *(const f32x4*)&xs[((ph + di) * 12 + pw + dj) * 68 + og * 4];
            #pragma unroll
            for (int i = 0; i < 4; i++) {
                acc[i][0] += xv[i] * wv[0];
                acc[i][1] += xv[i] * wv[1];
                acc[i][2] += xv[i] * wv[2];
                acc[i][3] += xv[i] * wv[3];
            }
        }

        #pragma unroll
        for (int i = 0; i < 4; i++) {
            int o = it * 64 + og * 4 + i;
            float bb = Bout[o];
            float2 v0 = make_float2(acc[i][0] + bb, acc[i][1] + bb);
            float2 v1 = make_float2(acc[i][2] + bb, acc[i][3] + bb);
            size_t zb = (((size_t)n * 256 + o) * 128 + 2 * gh) * 128 + 2 * gw;
            *(float2*)&Z[zb]       = v0;
            *(float2*)&Z[zb + 128] = v1;
        }
        if (!last) __syncthreads();   // xs re-written next chunk
    };

    chunk(0, xoA, xoB, false);
    chunk(1, xoB, xoA, false);
    chunk(2, xoA, xoB, false);
    chunk(3, xoB, xoA, true);
}

// ---------------------------------------------------------------------------
extern "C" void kernel_launch(void* const* d_in, const int* in_sizes, int n_in,
                              void* d_out, int out_size, void* d_ws, size_t ws_size,
                              hipStream_t stream) {
    const float* x      = (const float*)d_in[0];
    const float* w_down = (const float*)d_in[1];
    const float* b_down = (const float*)d_in[2];
    const float* w_enc  = (const float*)d_in[3];
    const float* b_enc  = (const float*)d_in[4];
    const float* w_out  = (const float*)d_in[5];
    const float* b_out  = (const float*)d_in[6];
    float* z = (float*)d_out;

    // workspace layout (ushort elements)
    ushort* t1T   = (ushort*)d_ws;          // 4*4096*128 = 2,097,152
    ushort* xoT   = t1T + 2097152;          // 4*4096*256 = 4,194,304
    ushort* wcomb = xoT + 4194304;          // 384*256    =    98,304
    ushort* wrb   = wcomb + 98304;          // 112*1152   =   129,024

    prep_kernel<<<888, 256, 0, stream>>>(w_down, w_out, w_enc, wcomb, wrb);
    dual_gemm_kernel<<<dim3(256, NB), 256, 0, stream>>>(x, wcomb, b_down, t1T, xoT);
    carafe_fused2_kernel<<<dim3(128, NB), 512, 0, stream>>>(t1T, wrb, b_enc, xoT, b_out, z);
}